// Round 6
// baseline (451.612 us; speedup 1.0000x reference)
//
#include <hip/hip_runtime.h>

// Cost volume: out[n,c,d,h,w] = left[n,c,h,w] * right[n,c,h,w-d] (w>=d else 0)
// N=2 C=32 H=136 W=240 D=48. Output 401 MB fp32.
//
// Round-8: RESUBMIT of round-7 (bench infra failed: "container failed twice";
// no counters, nothing learned). Rationale unchanged:
// R2/R3/R4/R6 all emit write chunks at exactly 127.5KiB stride (H*W*4) and all
// land at ~152-163us kernel residue regardless of LDS conflicts, NT-vs-plain,
// or 4x granule size -> granule-size row-thrash refuted. Remaining write-side
// suspect: the STRIDE PATTERN itself (channel/bank hash folding, L2 eviction
// order). fillBufferAligned (6.2 TB/s, same buffer) writes linearly. This
// kernel is write-pattern-identical to the fill: each block owns a CONTIGUOUS
// 192KiB output span swept front-to-back; (nc,d,h,w) decoded from the linear
// index via magic-mul divisions; left/right read through L1/L2 (16.7MB inputs,
// LLC-resident, coalesced reads). No LDS, no barrier, no stride in the stores.
// If this also lands ~410us total: write pattern exonerated -> next round is a
// double-launch probe to split kernel time from fixed harness overhead.

constexpr int W    = 240;
constexpr int H    = 136;
constexpr int D    = 48;
constexpr int W4   = W / 4;            // 60 float4 per row
constexpr int HW4  = H * W4;           // 8160 float4 per (nc,d) plane
constexpr int DHW4 = D * HW4;          // 391,680 float4 per nc
constexpr int ITERS  = 48;
constexpr int CHUNK4 = ITERS * 256;    // 12,288 float4 = 192KiB per block

typedef float v4f __attribute__((ext_vector_type(4)));
typedef float v2f __attribute__((ext_vector_type(2)));

__global__ __launch_bounds__(256) void cost_volume_kernel(
    const float* __restrict__ left,
    const float* __restrict__ right,
    float* __restrict__ out,
    int total4)
{
    const int base = blockIdx.x * CHUNK4 + threadIdx.x;
    v4f* __restrict__ O = reinterpret_cast<v4f*>(out);

    #pragma unroll 2
    for (int it = 0; it < ITERS; ++it) {
        const int i = base + it * 256;            // linear float4 index
        if (i >= total4) return;                  // exact fit at nc=64 (2040*12288)

        // decode i -> (nc, d, h, w4); unsigned magic-mul divisions
        const unsigned u   = (unsigned)i;
        const unsigned nc  = u / (unsigned)DHW4;
        const unsigned rem1 = u - nc * DHW4;
        const unsigned d   = rem1 / (unsigned)HW4;
        const unsigned rem2 = rem1 - d * HW4;
        const unsigned h   = rem2 / (unsigned)W4;
        const unsigned w4  = rem2 - h * W4;

        const unsigned row  = (nc * H + h) * W;   // float offset of row start
        const unsigned loff = row + 4 * w4;

        const v4f l4 = *reinterpret_cast<const v4f*>(left + loff);

        v4f r;
        if (w4 >= 12) {
            // 4*w4 - d >= 1: fully in-bounds; element loads let the compiler
            // pick the widest legal global_load form for the unaligned base.
            const float* __restrict__ Rp = right + (loff - d);
            r.x = Rp[0];
            r.y = Rp[1];
            r.z = Rp[2];
            r.w = Rp[3];
        } else {
            // boundary: clamped address + select (always-safe loads)
            const int off = (int)(4 * w4) - (int)d;
            const float* __restrict__ Rr = right + row;
            const float e0 = Rr[(off + 0 >= 0) ? off + 0 : 0];
            const float e1 = Rr[(off + 1 >= 0) ? off + 1 : 0];
            const float e2 = Rr[(off + 2 >= 0) ? off + 2 : 0];
            const float e3 = Rr[(off + 3 >= 0) ? off + 3 : 0];
            r.x = (off + 0 >= 0) ? e0 : 0.f;
            r.y = (off + 1 >= 0) ? e1 : 0.f;
            r.z = (off + 2 >= 0) ? e2 : 0.f;
            r.w = (off + 3 >= 0) ? e3 : 0.f;
        }
        O[i] = l4 * r;                            // 1KB dense per wave-store;
                                                  // block sweeps 192KiB linearly
    }
}

extern "C" void kernel_launch(void* const* d_in, const int* in_sizes, int n_in,
                              void* d_out, int out_size, void* d_ws, size_t ws_size,
                              hipStream_t stream) {
    const float* left  = (const float*)d_in[0];
    const float* right = (const float*)d_in[1];
    float* out = (float*)d_out;
    const int rows   = in_sizes[0] / W;     // N*C*H = 8704
    const int nc     = rows / H;            // N*C = 64
    const int total4 = nc * DHW4;           // 25,067,520
    const int nblocks = (total4 + CHUNK4 - 1) / CHUNK4;   // 2040 at nc=64
    cost_volume_kernel<<<nblocks, 256, 0, stream>>>(left, right, out, total4);
}

// Round 7
// 451.611 us; speedup vs baseline: 1.0000x; 1.0000x over previous
//
#include <hip/hip_runtime.h>

// Cost volume: out[n,c,d,h,w] = left[n,c,h,w] * right[n,c,h,w-d] (w>=d else 0)
// N=2 C=32 H=136 W=240 D=48. Output 401 MB fp32.
//
// Round-9: DIAGNOSTIC DOUBLE-PASS of the best kernel (R4 4-row tile, 152us
// residue). Every write-side theory is refuted: LDS conflicts (R3), NT vs
// plain (R4), 4x granule (R6), fully-linear fill-identical writes (R7, WORSE:
// 192us). The ~152us floor never moved. Remaining theories:
//   C: store write-allocate (RFO) doubles HBM traffic -> 820MB -> ~130us floor.
//      Signature: kernel FETCH_SIZE ~ 400MB.
//   B: kernel is actually ~70-90us; residue includes fixed harness overhead.
// We cannot distinguish them: the kernel's dispatch row has NEVER been visible
// (top-5 is all >=250us fills). This version stores the ENTIRE output TWICE
// (idempotent; asm memory clobber stops store-merging):
//   - dur_us - 409.9 = true single-pass kernel time (clean arithmetic probe)
//   - doubled dispatch (~2x true time) should crack the top-5 and expose
//     FETCH_SIZE / WRITE_SIZE / VALUBusy / Occupancy for the kernel itself.
// Everything else is byte-identical to R4.

constexpr int W    = 240;
constexpr int H    = 136;
constexpr int D    = 48;
constexpr int W4   = W / 4;          // 60 float4 per row
constexpr int ROWS = 4;              // h-rows per block
constexpr int NT   = H / ROWS;       // 34 h-tiles
constexpr int PAD  = D;              // 48 zero floats of left padding
constexpr int CLEN = PAD + W;        // 288 floats per shifted copy
constexpr int RTOT = 4 * ROWS * CLEN; // 4608 staged right floats

typedef float v4f __attribute__((ext_vector_type(4)));

__global__ __launch_bounds__(256) void cost_volume_kernel(
    const float* __restrict__ left,
    const float* __restrict__ right,
    float* __restrict__ out)
{
    __shared__ __align__(16) float sL[ROWS * W];
    __shared__ __align__(16) float sR[4][ROWS][CLEN];

    const int ht  = blockIdx.x;      // 0..NT-1
    const int nc  = blockIdx.y;      // 0..NC-1
    const int h0  = ht * ROWS;
    const int tid = threadIdx.x;

    const float* __restrict__ Lg = left  + (size_t)(nc * H + h0) * W;
    const float* __restrict__ Rg = right + (size_t)(nc * H + h0) * W;

    if (tid < ROWS * W4) {
        reinterpret_cast<v4f*>(sL)[tid] =
            reinterpret_cast<const v4f*>(Lg)[tid];
    }
    for (int y = tid; y < RTOT; y += 256) {
        const int j   = y / (ROWS * CLEN);
        const int rem = y - j * (ROWS * CLEN);
        const int r   = rem / CLEN;
        const int x   = rem - r * CLEN;
        const int src = x - PAD - j;
        sR[0][0][y] = (src >= 0) ? Rg[r * W + src] : 0.0f;
    }
    __syncthreads();

    if (tid >= ROWS * W4) return;    // 240 active threads

    const int r  = tid / W4;
    const int w4 = tid - r * W4;

    const v4f l4 = reinterpret_cast<const v4f*>(sL)[tid];

    v4f* __restrict__ o = reinterpret_cast<v4f*>(out)
        + ((size_t)nc * D * H + (h0 + r)) * (size_t)W4 + w4;
    const size_t ds4 = (size_t)H * W4;

    const v4f* C0 = reinterpret_cast<const v4f*>(sR[0][r]);
    const v4f* C1 = reinterpret_cast<const v4f*>(sR[1][r]);
    const v4f* C2 = reinterpret_cast<const v4f*>(sR[2][r]);
    const v4f* C3 = reinterpret_cast<const v4f*>(sR[3][r]);

    // DIAGNOSTIC: write the whole output twice (idempotent). The asm memory
    // clobber prevents the compiler from eliminating the first pass.
    #pragma unroll 1
    for (int pass = 0; pass < 2; ++pass) {
        #pragma unroll
        for (int q = 0; q < D / 4; ++q) {
            const int base = w4 + PAD / 4 - q;     // aligned b128, conflict-free
            const v4f r0 = C0[base];
            const v4f r1 = C1[base];
            const v4f r2 = C2[base];
            const v4f r3 = C3[base];
            v4f* oq = o + (size_t)(4 * q) * ds4;
            oq[0]       = l4 * r0;
            oq[ds4]     = l4 * r1;
            oq[2 * ds4] = l4 * r2;
            oq[3 * ds4] = l4 * r3;
        }
        asm volatile("" ::: "memory");
    }
}

extern "C" void kernel_launch(void* const* d_in, const int* in_sizes, int n_in,
                              void* d_out, int out_size, void* d_ws, size_t ws_size,
                              hipStream_t stream) {
    const float* left  = (const float*)d_in[0];
    const float* right = (const float*)d_in[1];
    float* out = (float*)d_out;
    const int rows = in_sizes[0] / W;   // N*C*H = 8704
    const int nc   = rows / H;          // N*C = 64
    dim3 grid(NT, nc);
    cost_volume_kernel<<<grid, 256, 0, stream>>>(left, right, out);
}